// Round 11
// baseline (268.494 us; speedup 1.0000x reference)
//
#include <hip/hip_runtime.h>
#include <hip/hip_bf16.h>

#define B_ 32
#define T_ 1000
#define H_ 512
#define V_ 2048
#define L_ 100
#define M_ (B_*T_)          // 32000 rows
#define GSTRIDE 104         // p_ext row stride (floats): [0]=blank, [2+l]=label l
#define LOG2E 1.4426950408889634f
#define LSE_SHIFT 48.0f
#define BIAS60 1.152921504606847e18f   // 2^60

typedef __attribute__((ext_vector_type(8))) short bf16x8;
typedef __attribute__((ext_vector_type(4))) float f32x4;

#define AS_G(p)  ((const __attribute__((address_space(1))) unsigned int*)(p))
#define AS_L(p)  ((__attribute__((address_space(3))) unsigned int*)(p))

__device__ __forceinline__ unsigned short f2bf(float x) {
    unsigned int u; __builtin_memcpy(&u, &x, 4);
    unsigned int r = (u + 0x7fffu + ((u >> 16) & 1u)) >> 16;   // RNE
    return (unsigned short)r;
}

// DPP helpers (verified R3/R5/R9).
__device__ __forceinline__ float dpp_shr1(float x) {          // lane i <- lane i-1, lane0 <- 0
    int r = __builtin_amdgcn_update_dpp(0, __builtin_bit_cast(int, x), 0x138, 0xf, 0xf, false);
    return __builtin_bit_cast(float, r);
}
template<int CTRL>
__device__ __forceinline__ float fmax_dpp(float x) {          // zero-fill ok: operands >= 0
    int s = __builtin_amdgcn_update_dpp(0, __builtin_bit_cast(int, x), CTRL, 0xf, 0xf, false);
    return fmaxf(x, __builtin_bit_cast(float, s));
}
__device__ __forceinline__ float wave_max_nonneg(float x) {   // max over 64 lanes, broadcast
    x = fmax_dpp<0x111>(x);
    x = fmax_dpp<0x112>(x);
    x = fmax_dpp<0x114>(x);
    x = fmax_dpp<0x118>(x);
    x = fmax_dpp<0x142>(x);
    x = fmax_dpp<0x143>(x);
    return __builtin_bit_cast(float, __builtin_amdgcn_readlane(__builtin_bit_cast(int, x), 63));
}
template<int CTRL>
__device__ __forceinline__ float fadd_dpp(float x) {          // zero-fill = additive identity
    int s = __builtin_amdgcn_update_dpp(0, __builtin_bit_cast(int, x), CTRL, 0xf, 0xf, false);
    return x + __builtin_bit_cast(float, s);
}
__device__ __forceinline__ float rowsum16(float x) {          // sum over 16-lane row -> lane m==15
    x = fadd_dpp<0x111>(x);
    x = fadd_dpp<0x112>(x);
    x = fadd_dpp<0x114>(x);
    x = fadd_dpp<0x118>(x);
    return x;
}

// ---------------------------------------------------------------------------
// Kernel 0: zero out + Srow, convert eouts/W fp32 -> bf16 into ws
// ---------------------------------------------------------------------------
__global__ __launch_bounds__(256) void prep_kernel(
        const float* __restrict__ eouts, const float* __restrict__ W,
        unsigned short* __restrict__ eb, unsigned short* __restrict__ wb,
        float* __restrict__ Srow, float* __restrict__ out)
{
    const int E4 = M_*H_/4;      // 4,096,000
    const int W4 = V_*H_/4;      //   262,144
    const int S4 = M_/4;         //     8,000
    int idx = blockIdx.x*256 + threadIdx.x;
    if (idx == 0) out[0] = 0.f;
    if (idx < E4) {
        float4 v = ((const float4*)eouts)[idx];
        ushort4 o; o.x=f2bf(v.x); o.y=f2bf(v.y); o.z=f2bf(v.z); o.w=f2bf(v.w);
        ((ushort4*)eb)[idx] = o;
    } else if (idx < E4 + W4) {
        int j = idx - E4;
        float4 v = ((const float4*)W)[j];
        ushort4 o; o.x=f2bf(v.x); o.y=f2bf(v.y); o.z=f2bf(v.z); o.w=f2bf(v.w);
        ((ushort4*)wb)[j] = o;
    } else if (idx < E4 + W4 + S4) {
        int j = idx - E4 - W4;
        ((float4*)Srow)[j] = make_float4(0.f,0.f,0.f,0.f);
    }
}

// ---------------------------------------------------------------------------
// Kernel 1: bf16 MFMA GEMM + fused row-sum of 2^(z*log2e - 48).
// R11: merged 4-phase schedule — halves barrier count (8 vs 16 per 2
// K-tiles), 32 MFMA per phase. Theory: R5's ~960 cyc/phase non-MFMA
// overhead is dominated by per-barrier fixed cost (round-trip + 8-wave
// skew); R7/R8 ruled out lgkm-drain and lockstep-vs-coresidency.
// Safety (re-derived): P1{read B0+A0q3q2 | stage A1r0,r2@k1},
// P2{read A0q1q0 | stage B0x4+A0r1,r3@k2}, P3{read B1+A1q3q2 |
// stage A0r0,r2@k2}, P4{read A1q1q0 | stage B1x4+A1r1,r3@k3}.
// Every staged region is dead >=1 closing barrier before its write;
// stages issue only after the reader phase's closing barrier.
// vmcnt(8) at EVERY phase end (issues 2,6,2,6/phase): keeping the 8
// newest lands exactly the loads the next phase reads (verified per
// phase + prologue). Last iter: vmcnt(0) at P2/P3/P4.
// WAIT_LGKM pinning kept verbatim (load-bearing, R4/R7 evidence).
// XCD-grouped grid + rowsum16 epilogue unchanged (R5-proven).
// ---------------------------------------------------------------------------
__global__ __launch_bounds__(512, 1) void gemm_lse_kernel(
        const unsigned short* __restrict__ eb, const unsigned short* __restrict__ wb,
        const float* __restrict__ bias, float* __restrict__ Srow)
{
    __shared__ __align__(16) unsigned short Ab[2][256*64];
    __shared__ __align__(16) unsigned short Bb[2][256*64];
    __shared__ float rs[256];
    const int tid  = threadIdx.x;
    const int w    = tid >> 6;      // 0..7
    const int lane = tid & 63;
    const int m    = lane & 15;
    const int qh   = lane >> 4;     // 0..3
    const int wr   = w >> 2;        // 0..1  (M half)
    const int wc   = w & 3;         // 0..3  (N quarter)
    const int rl   = m & 7;
    const int lrow = lane >> 3;     // 0..7 staging row within 8-row wave slice
    const int k8   = ((lane & 7) ^ lrow) * 8;   // pre-swizzled source chunk
    const int lin   = blockIdx.x;               // 0..255 (XCD = lin%8 = ytile%8)
    const int ytile = lin & 31;
    const int nbase = (lin >> 5) * 256;
    const int ntiles = (124 - ytile)/32 + 1;    // 125 M-tiles over 32 y-slots
    int mb_cur = ytile * 256;

    if (tid < 256) rs[tid] = 0.f;

    float bv[4];
    #pragma unroll
    for (int ni=0;ni<4;ni++) bv[ni] = bias[nbase + wc*64 + ni*16 + m];

    f32x4 acc[8][4];
    #pragma unroll
    for (int i=0;i<8;i++)
        #pragma unroll
        for (int j=0;j<4;j++) acc[i][j] = (f32x4){0.f,0.f,0.f,0.f};
    bf16x8 af2[4][2], bfr[4][2];

#define STAGE_A(sel, r, kt, mb) do { \
        const unsigned short* _s = eb + (size_t)((mb) + (r)*64 + w*8 + lrow)*H_ + (kt)*64 + k8; \
        __builtin_amdgcn_global_load_lds(AS_G(_s), AS_L(&Ab[sel][((r)*64 + w*8)*64]), 16, 0, 0); \
    } while(0)
#define STAGE_B(sel, r, kt) do { \
        const unsigned short* _s = wb + (size_t)(nbase + (r)*64 + w*8 + lrow)*H_ + (kt)*64 + k8; \
        __builtin_amdgcn_global_load_lds(AS_G(_s), AS_L(&Bb[sel][((r)*64 + w*8)*64]), 16, 0, 0); \
    } while(0)

#define LOADB(sel) \
    _Pragma("unroll") \
    for (int ni=0; ni<4; ++ni) { \
        const int brow = wc*64 + ni*16 + m; \
        bfr[ni][0] = *(const bf16x8*)(&Bb[sel][brow*64 + ((qh ^ rl))*8]); \
        bfr[ni][1] = *(const bf16x8*)(&Bb[sel][brow*64 + (((4+qh) ^ rl))*8]); \
    }
// load A fragments for TWO quadrants: acc rows qlo*2 .. qlo*2+3
#define LOADA2(sel, qlo) \
    _Pragma("unroll") \
    for (int a=0; a<4; ++a) { \
        const int arow = wr*128 + ((qlo)*2+a)*16 + m; \
        af2[a][0] = *(const bf16x8*)(&Ab[sel][arow*64 + ((qh ^ rl))*8]); \
        af2[a][1] = *(const bf16x8*)(&Ab[sel][arow*64 + (((4+qh) ^ rl))*8]); \
    }
// 32 MFMA covering acc rows qlo*2 .. qlo*2+3 (two quadrants, K=64)
#define MFMA32(qlo) \
    __builtin_amdgcn_s_setprio(1); \
    _Pragma("unroll") \
    for (int a=0; a<4; ++a) \
        _Pragma("unroll") \
        for (int ni=0; ni<4; ++ni) { \
            acc[(qlo)*2+a][ni] = __builtin_amdgcn_mfma_f32_16x16x32_bf16(af2[a][0], bfr[ni][0], acc[(qlo)*2+a][ni], 0, 0, 0); \
            acc[(qlo)*2+a][ni] = __builtin_amdgcn_mfma_f32_16x16x32_bf16(af2[a][1], bfr[ni][1], acc[(qlo)*2+a][ni], 0, 0, 0); \
        } \
    __builtin_amdgcn_s_setprio(0);
#define BARX() __builtin_amdgcn_s_barrier()
#define WAIT_LGKM() do { asm volatile("s_waitcnt lgkmcnt(0)" ::: "memory"); \
                         __builtin_amdgcn_sched_barrier(0); } while(0)
#define VMC8()  asm volatile("s_waitcnt vmcnt(8)" ::: "memory")
#define VMC0()  asm volatile("s_waitcnt vmcnt(0)" ::: "memory")

    // ---- prologue: K-tile 0 -> buf0 (all), K-tile 1 -> buf1 (B + Ar1,Ar3)
    // Order: B0x4, A0r1,A0r3, A0r0,A0r2, B1x4, A1r1,A1r3  (14 loads).
    // vmcnt(8) lands the 6 oldest = B0 + A0r1,r3 = exactly P1's reads.
    STAGE_B(0,0,0); STAGE_B(0,1,0);
    STAGE_B(0,2,0); STAGE_B(0,3,0);
    STAGE_A(0,1,0,mb_cur); STAGE_A(0,3,0,mb_cur);
    STAGE_A(0,0,0,mb_cur); STAGE_A(0,2,0,mb_cur);
    STAGE_B(1,0,1); STAGE_B(1,1,1);
    STAGE_B(1,2,1); STAGE_B(1,3,1);
    STAGE_A(1,1,1,mb_cur); STAGE_A(1,3,1,mb_cur);
    VMC8();
    BARX();

    #pragma unroll 1
    for (int mt = 0; mt < ntiles; ++mt) {
        const int mb_nxt = (ytile + 32*(mt+1)) * 256;  // used only when staged
        #pragma unroll 1
        for (int it = 0; it < 4; ++it) {
            const bool last = (mt == ntiles-1) && (it == 3);
            const int k1 = 2*it + 1;                   // buf1 A (current tile)
            const int k2 = (2*it + 2) & 7;             // rolls to next tile's kt0
            const int k3 = (2*it + 3) & 7;             // rolls to next tile's kt1
            const int mbs = (it < 3) ? mb_cur : mb_nxt;
            // ---- P1: buf0 q3+q2 (regions 1,3) | stage buf1.Ar0,Ar2 (k1)
            LOADB(0) LOADA2(0,2)
            STAGE_A(1,0,k1,mb_cur); STAGE_A(1,2,k1,mb_cur);
            BARX(); WAIT_LGKM();
            MFMA32(2)
            VMC8();
            BARX();
            // ---- P2: buf0 q1+q0 (regions 0,2) | stage buf0.B x4 + Ar1,Ar3 (k2)
            LOADA2(0,0)
            if (!last) {
                STAGE_B(0,0,k2); STAGE_B(0,1,k2);
                STAGE_B(0,2,k2); STAGE_B(0,3,k2);
                STAGE_A(0,1,k2,mbs); STAGE_A(0,3,k2,mbs);
            }
            BARX(); WAIT_LGKM();
            MFMA32(0)
            if (!last) VMC8(); else VMC0();
            BARX();
            // ---- P3: buf1 q3+q2 | stage buf0.Ar0,Ar2 (k2)
            LOADB(1) LOADA2(1,2)
            if (!last) { STAGE_A(0,0,k2,mbs); STAGE_A(0,2,k2,mbs); }
            BARX(); WAIT_LGKM();
            MFMA32(2)
            if (!last) VMC8(); else VMC0();
            BARX();
            // ---- P4: buf1 q1+q0 | stage buf1.B x4 + Ar1,Ar3 (k3)
            LOADA2(1,0)
            if (!last) {
                STAGE_B(1,0,k3); STAGE_B(1,1,k3);
                STAGE_B(1,2,k3); STAGE_B(1,3,k3);
                STAGE_A(1,1,k3,mbs); STAGE_A(1,3,k3,mbs);
            }
            BARX(); WAIT_LGKM();
            MFMA32(0)
            if (!last) VMC8(); else VMC0();
            BARX();
        }

        // ---- epilogue for mb_cur: bias + exp2 row-sum, DPP rowsum16 (VALU)
        // -> LDS atomic from m==15 lanes -> coalesced tid<256 global atomic.
        {
            #pragma unroll
            for (int mi=0;mi<8;mi++) {
                #pragma unroll
                for (int r=0;r<4;r++) {
                    float s = 0.f;
                    #pragma unroll
                    for (int ni=0;ni<4;ni++)
                        s += exp2f((acc[mi][ni][r] + bv[ni]) * LOG2E - LSE_SHIFT);
                    s = rowsum16(s);
                    if (m == 15) atomicAdd(&rs[wr*128 + mi*16 + qh*4 + r], s);
                }
            }
            WAIT_LGKM();
            BARX();
            if (tid < 256) {
                atomicAdd(&Srow[mb_cur + tid], rs[tid]);
                rs[tid] = 0.f;
            }
            #pragma unroll
            for (int i=0;i<8;i++)
                #pragma unroll
                for (int j=0;j<4;j++) acc[i][j] = (f32x4){0.f,0.f,0.f,0.f};
        }
        mb_cur = mb_nxt;
    }
#undef STAGE_A
#undef STAGE_B
#undef LOADB
#undef LOADA2
#undef MFMA32
#undef BARX
#undef WAIT_LGKM
#undef VMC8
#undef VMC0
}

// ---------------------------------------------------------------------------
// Kernel 2: gather ext-label probs via MFMA (B-rows gathered by vocab id),
// same XOR bank swizzle as kernel 1 (unchanged).
// ---------------------------------------------------------------------------
__global__ __launch_bounds__(256) void gather_mfma_kernel(
        const unsigned short* __restrict__ eb, const unsigned short* __restrict__ wb,
        const float* __restrict__ bias, const int* __restrict__ ys,
        const float* __restrict__ Srow, float* __restrict__ g)
{
    __shared__ __align__(16) unsigned short As[128*64];
    __shared__ __align__(16) unsigned short Bs[128*64];
    __shared__ float ls[128];
    const int tid  = threadIdx.x;
    const int w    = tid >> 6;
    const int lane = tid & 63;
    const int m    = lane & 15;
    const int q    = lane >> 4;
    const int wrow = w >> 1;
    const int wcol = w & 1;
    const int b    = blockIdx.y;
    const int tb   = blockIdx.x * 128;

    if (tid < 128) {
        int t = tb + tid;
        ls[tid] = (t < T_) ? (LSE_SHIFT + log2f(Srow[b*T_ + t])) : 0.f;
    }

    const int rbase = w*32 + (lane >> 3);
    const int k8    = (((lane & 7) ^ ((lane >> 3) & 7)) * 8);
    const int rl    = m & 7;

    int vrow[4];
    #pragma unroll
    for (int j=0;j<4;++j) {
        int labr = rbase + j*8;
        vrow[j] = (labr == 0 || labr > L_) ? 0 : ys[b*L_ + labr - 1];
    }
    int labc[4]; float bv[4];
    #pragma unroll
    for (int ni=0;ni<4;++ni) {
        int lab = wcol*64 + ni*16 + m;
        labc[ni] = lab;
        int v = (lab == 0 || lab > L_) ? 0 : ys[b*L_ + lab - 1];
        bv[ni] = bias[v];
    }

    f32x4 acc[4][4];
    #pragma unroll
    for (int i=0;i<4;i++)
        #pragma unroll
        for (int j=0;j<4;j++) acc[i][j] = (f32x4){0.f,0.f,0.f,0.f};

    for (int kc = 0; kc < 8; ++kc) {
        __syncthreads();
        #pragma unroll
        for (int j = 0; j < 4; ++j) {
            const unsigned short* ga = eb + (size_t)(b*T_ + tb + rbase + j*8)*H_ + kc*64 + k8;
            __builtin_amdgcn_global_load_lds(AS_G(ga), AS_L(As + (w*4+j)*512), 16, 0, 0);
            const unsigned short* gw = wb + (size_t)vrow[j]*H_ + kc*64 + k8;
            __builtin_amdgcn_global_load_lds(AS_G(gw), AS_L(Bs + (w*4+j)*512), 16, 0, 0);
        }
        __syncthreads();
        #pragma unroll
        for (int kk = 0; kk < 2; ++kk) {
            const int sw = ((kk*4 + q) ^ rl) * 8;
            bf16x8 af[4], bfr[4];
            #pragma unroll
            for (int mi=0;mi<4;mi++)
                af[mi] = *(const bf16x8*)(As + (wrow*8 + mi*2 + (m>>3))*512 + rl*64 + sw);
            #pragma unroll
            for (int ni=0;ni<4;ni++)
                bfr[ni] = *(const bf16x8*)(Bs + (wcol*8 + ni*2 + (m>>3))*512 + rl*64 + sw);
            #pragma unroll
            for (int mi=0;mi<4;mi++)
                #pragma unroll
                for (int ni=0;ni<4;ni++)
                    acc[mi][ni] = __builtin_amdgcn_mfma_f32_16x16x32_bf16(
                        af[mi], bfr[ni], acc[mi][ni], 0, 0, 0);
        }
    }

    #pragma unroll
    for (int mi=0;mi<4;mi++) {
        #pragma unroll
        for (int r=0;r<4;r++) {
            int trow = wrow*64 + mi*16 + q*4 + r;
            int t = tb + trow;
            float l2 = ls[trow];
            #pragma unroll
            for (int ni=0;ni<4;ni++) {
                if (t < T_ && labc[ni] <= L_) {
                    float p = exp2f((acc[mi][ni][r] + bv[ni]) * LOG2E - l2);
                    int off = (labc[ni] == 0) ? 0 : labc[ni] + 1;
                    g[(size_t)(b*T_ + t)*GSTRIDE + off] = p;
                }
            }
        }
    }
}

// ---------------------------------------------------------------------------
// Kernel 3: CTC forward DP — producer/consumer waves, barrier-ordered
// (R5 version — best measured total; unchanged).
// ---------------------------------------------------------------------------
__global__ __launch_bounds__(128, 1) void ctc_dp_kernel(
        const float* __restrict__ g, const int* __restrict__ ys,
        const int* __restrict__ elens, const int* __restrict__ ylens,
        float* __restrict__ out)
{
    __shared__ __align__(16) float ring[2*2048];   // 2 sets x 8 pair-slots x 1KB
    const int b    = blockIdx.x;
    const int tid  = threadIdx.x;
    const int wv   = tid >> 6;
    const int lane = tid & 63;
    const float* gb = g + (size_t)b * T_ * GSTRIDE;
    const int ylen = ylens[b];
    const int elen = elens[b];
    const int kmax = (elen - 1) >> 4;

    const int Sv   = 2*ylen + 1;
    const int s0   = 4*lane;
    const float msk0 = (s0   < Sv) ? 1.f : 0.f;
    const float msk1 = (s0+1 < Sv) ? 1.f : 0.f;
    const float msk2 = (s0+2 < Sv) ? 1.f : 0.f;
    const float msk3 = (s0+3 < Sv) ? 1.f : 0.f;
    const int l0 = 2*lane, l1 = 2*lane + 1;
    int i0 = min(max(l0,1), L_-1);
    int i1 = min(l1, L_-1);
    const float sk1 = (l0 >= 1 && l0 < L_ && ys[b*L_+i0] != ys[b*L_+i0-1]) ? 1.f : 0.f;
    const float sk3 = (l1 < L_        && ys[b*L_+i1] != ys[b*L_+i1-1]) ? 1.f : 0.f;

    float a0 = 0.f, a1 = 0.f, a2 = 0.f, a3 = 0.f, C2 = 0.f;
    if (wv == 0) {
        a0 = (lane == 0) ? gb[0] : 0.f;     // t=0 init
        a1 = (lane == 0) ? gb[2] : 0.f;
    } else {
        #pragma unroll
        for (int s = 0; s < 8; ++s) {
            int srow = min(2*s, T_-2);
            __builtin_amdgcn_global_load_lds(AS_G(gb + (size_t)srow*GSTRIDE + 4*lane),
                                             AS_L(ring + s*256), 16, 0, 0);
        }
    }

    auto dpstep = [&](float p0, float p1, float p2, float p3) {
        float um1 = dpp_shr1(a3);
        float n0 = a0 + um1;
        float n1 = a1 + a0 + sk1*um1;
        float n2 = a2 + a1;
        float n3 = a3 + a2 + sk3*a1;
        a0 = n0*p0; a1 = n1*p1; a2 = n2*p2; a3 = n3*p3;
    };
    auto renorm = [&]() {
        float mm = wave_max_nonneg(fmaxf(fmaxf(a0,a1), fmaxf(a2,a3)));
        if (mm > 0.f) {
            float rr = fminf(__fdividef(BIAS60, mm), 3.0e38f);
            C2 -= __log2f(rr);
            a0 *= rr; a1 *= rr; a2 *= rr; a3 *= rr;
        }
    };

    __syncthreads();                                  // burst 0 landed

    for (int k = 0; k <= kmax; ++k) {
        if (wv == 1) {
            if (k < kmax) {
                float* dset = ring + ((k+1) & 1)*2048;
                int pbase = 8*(k + 1);
                #pragma unroll
                for (int s = 0; s < 8; ++s) {
                    int srow = min(2*(pbase + s), T_-2);
                    __builtin_amdgcn_global_load_lds(AS_G(gb + (size_t)srow*GSTRIDE + 4*lane),
                                                     AS_L(dset + s*256), 16, 0, 0);
                }
            }
        } else {
            const float* sb = ring + (k & 1)*2048;
            float P0[16], P1[16], P2[16], P3[16];
            #pragma unroll
            for (int s = 0; s < 8; ++s) {
                const float* slot = sb + s*256;
                float pb0 = slot[0];
                float pb1 = slot[104];
                float2 lo = *(const float2*)(slot + 2  + 2*lane);
                float2 hi = *(const float2*)(slot + 106 + 2*lane);
                P0[2*s]   = pb0*msk0; P1[2*s]   = lo.x*msk1;
                P2[2*s]   = pb0*msk2; P3[2*s]   = lo.y*msk3;
                P0[2*s+1] = pb1*msk0; P1[2*s+1] = hi.x*msk1;
                P2[2*s+1] = pb1*msk2; P3[2*s+1] = hi.y*msk3;
            }
            const int t0 = 16*k;
            #pragma unroll
            for (int j = 0; j < 16; ++j) {
                int t = t0 + j;
                if (t > 0 && t < elen)
                    dpstep(P0[j], P1[j], P2[j], P3[j]);
                if ((j & 7) == 7) renorm();
            }
        }
        __syncthreads();
    }

    if (wv == 0) {
        int sA = 2*ylen, sB = sA - 1;
        float vA = __shfl((sA & 2) ? a2 : a0, sA >> 2);
        float vB = __shfl((sB & 2) ? a3 : a1, sB >> 2);
        if (lane == 0) {
            float sum = vA + vB;
            float loss = 0.f;
            if (sum > 0.f) {
                loss = -(log2f(sum) + C2) * 0.6931471805599453f;
                if (!(loss < 5e9f)) loss = 0.f;         // zero_infinity
            }
            atomicAdd(out, loss * (1.0f/B_));
        }
    }
}

// ---------------------------------------------------------------------------
extern "C" void kernel_launch(void* const* d_in, const int* in_sizes, int n_in,
                              void* d_out, int out_size, void* d_ws, size_t ws_size,
                              hipStream_t stream)
{
    const float* eouts = (const float*)d_in[0];
    const float* W     = (const float*)d_in[1];
    const float* bias  = (const float*)d_in[2];
    const int*   ys    = (const int*)d_in[3];
    const int*   elens = (const int*)d_in[4];
    const int*   ylens = (const int*)d_in[5];
    float* out = (float*)d_out;

    char* ws = (char*)d_ws;
    unsigned short* eb = (unsigned short*)ws;                  // 32,768,000 B
    unsigned short* wb = (unsigned short*)(ws + 32768000);     //  2,097,152 B
    float* Srow        = (float*)(ws + 34865152);              //    128,000 B
    float* g           = (float*)(ws + 34993152);              // 13,312,000 B

    prep_kernel<<<17057, 256, 0, stream>>>(eouts, W, eb, wb, Srow, out);
    gemm_lse_kernel<<<256, 512, 0, stream>>>(eb, wb, bias, Srow);
    gather_mfma_kernel<<<dim3(8, 32), 256, 0, stream>>>(eb, wb, bias, ys, Srow, g);
    ctc_dp_kernel<<<B_, 128, 0, stream>>>(g, ys, elens, ylens, out);
}

// Round 12
// 264.870 us; speedup vs baseline: 1.0137x; 1.0137x over previous
//
#include <hip/hip_runtime.h>
#include <hip/hip_bf16.h>

#define B_ 32
#define T_ 1000
#define H_ 512
#define V_ 2048
#define L_ 100
#define M_ (B_*T_)          // 32000 rows
#define GSTRIDE 104         // p_ext row stride (floats): [0]=blank, [2+l]=label l
#define LOG2E 1.4426950408889634f
#define LSE_SHIFT 48.0f
#define BIAS60 1.152921504606847e18f   // 2^60

typedef __attribute__((ext_vector_type(8))) short bf16x8;
typedef __attribute__((ext_vector_type(4))) float f32x4;

#define AS_G(p)  ((const __attribute__((address_space(1))) unsigned int*)(p))
#define AS_L(p)  ((__attribute__((address_space(3))) unsigned int*)(p))

__device__ __forceinline__ unsigned short f2bf(float x) {
    unsigned int u; __builtin_memcpy(&u, &x, 4);
    unsigned int r = (u + 0x7fffu + ((u >> 16) & 1u)) >> 16;   // RNE
    return (unsigned short)r;
}

// DPP helpers (verified R3/R5/R9).
__device__ __forceinline__ float dpp_shr1(float x) {          // lane i <- lane i-1, lane0 <- 0
    int r = __builtin_amdgcn_update_dpp(0, __builtin_bit_cast(int, x), 0x138, 0xf, 0xf, false);
    return __builtin_bit_cast(float, r);
}
template<int CTRL>
__device__ __forceinline__ float fmax_dpp(float x) {          // zero-fill ok: operands >= 0
    int s = __builtin_amdgcn_update_dpp(0, __builtin_bit_cast(int, x), CTRL, 0xf, 0xf, false);
    return fmaxf(x, __builtin_bit_cast(float, s));
}
__device__ __forceinline__ float wave_max_nonneg(float x) {   // max over 64 lanes, broadcast
    x = fmax_dpp<0x111>(x);
    x = fmax_dpp<0x112>(x);
    x = fmax_dpp<0x114>(x);
    x = fmax_dpp<0x118>(x);
    x = fmax_dpp<0x142>(x);
    x = fmax_dpp<0x143>(x);
    return __builtin_bit_cast(float, __builtin_amdgcn_readlane(__builtin_bit_cast(int, x), 63));
}
template<int CTRL>
__device__ __forceinline__ float fadd_dpp(float x) {          // zero-fill = additive identity
    int s = __builtin_amdgcn_update_dpp(0, __builtin_bit_cast(int, x), CTRL, 0xf, 0xf, false);
    return x + __builtin_bit_cast(float, s);
}
__device__ __forceinline__ float rowsum16(float x) {          // sum over 16-lane row -> lane m==15
    x = fadd_dpp<0x111>(x);
    x = fadd_dpp<0x112>(x);
    x = fadd_dpp<0x114>(x);
    x = fadd_dpp<0x118>(x);
    return x;
}

// ---------------------------------------------------------------------------
// Kernel 0: zero out + Srow, convert eouts/W fp32 -> bf16 into ws
// ---------------------------------------------------------------------------
__global__ __launch_bounds__(256) void prep_kernel(
        const float* __restrict__ eouts, const float* __restrict__ W,
        unsigned short* __restrict__ eb, unsigned short* __restrict__ wb,
        float* __restrict__ Srow, float* __restrict__ out)
{
    const int E4 = M_*H_/4;      // 4,096,000
    const int W4 = V_*H_/4;      //   262,144
    const int S4 = M_/4;         //     8,000
    int idx = blockIdx.x*256 + threadIdx.x;
    if (idx == 0) out[0] = 0.f;
    if (idx < E4) {
        float4 v = ((const float4*)eouts)[idx];
        ushort4 o; o.x=f2bf(v.x); o.y=f2bf(v.y); o.z=f2bf(v.z); o.w=f2bf(v.w);
        ((ushort4*)eb)[idx] = o;
    } else if (idx < E4 + W4) {
        int j = idx - E4;
        float4 v = ((const float4*)W)[j];
        ushort4 o; o.x=f2bf(v.x); o.y=f2bf(v.y); o.z=f2bf(v.z); o.w=f2bf(v.w);
        ((ushort4*)wb)[j] = o;
    } else if (idx < E4 + W4 + S4) {
        int j = idx - E4 - W4;
        ((float4*)Srow)[j] = make_float4(0.f,0.f,0.f,0.f);
    }
}

// ---------------------------------------------------------------------------
// Kernel 1: bf16 MFMA GEMM + fused row-sum of 2^(z*log2e - 48).
// Session-best structure (R5, 84 µs, three independent reproductions):
// 256x256 persistent tile, BK=64, 8 waves, 8-phase counted-vmcnt schedule,
// WAIT_LGKM pinning after each opening barrier, XCD-grouped 1-D grid,
// rowsum16 DPP epilogue via LDS rs[] + coalesced tid<256 global atomic.
// CLOSED LEDGER (do not re-try): deeper pipeline (R2 null), drain removal
// (R7 −27%), scattered atomics (R4 −15%), 2-block co-residency (R8 −10%),
// merged 4-phase / halved barriers (R11 −29%). Persistent rollover (R3,
// +13%) and XCD grouping (R4, FETCH 132->24 MB) are the keepers. The fine
// {small ds_read burst | 16 MFMA} alternation is load-bearing (m196-class).
// ---------------------------------------------------------------------------
__global__ __launch_bounds__(512, 1) void gemm_lse_kernel(
        const unsigned short* __restrict__ eb, const unsigned short* __restrict__ wb,
        const float* __restrict__ bias, float* __restrict__ Srow)
{
    __shared__ __align__(16) unsigned short Ab[2][256*64];
    __shared__ __align__(16) unsigned short Bb[2][256*64];
    __shared__ float rs[256];
    const int tid  = threadIdx.x;
    const int w    = tid >> 6;      // 0..7
    const int lane = tid & 63;
    const int m    = lane & 15;
    const int qh   = lane >> 4;     // 0..3
    const int wr   = w >> 2;        // 0..1  (M half)
    const int wc   = w & 3;         // 0..3  (N quarter)
    const int rl   = m & 7;
    const int lrow = lane >> 3;     // 0..7 staging row within 8-row wave slice
    const int k8   = ((lane & 7) ^ lrow) * 8;   // pre-swizzled source chunk
    const int lin   = blockIdx.x;               // 0..255 (XCD = lin%8 = ytile%8)
    const int ytile = lin & 31;
    const int nbase = (lin >> 5) * 256;
    const int ntiles = (124 - ytile)/32 + 1;    // 125 M-tiles over 32 y-slots
    int mb_cur = ytile * 256;

    if (tid < 256) rs[tid] = 0.f;

    float bv[4];
    #pragma unroll
    for (int ni=0;ni<4;ni++) bv[ni] = bias[nbase + wc*64 + ni*16 + m];

    f32x4 acc[8][4];
    #pragma unroll
    for (int i=0;i<8;i++)
        #pragma unroll
        for (int j=0;j<4;j++) acc[i][j] = (f32x4){0.f,0.f,0.f,0.f};
    bf16x8 af[2][2], bfr[4][2];

#define STAGE_A(sel, r, kt, mb) do { \
        const unsigned short* _s = eb + (size_t)((mb) + (r)*64 + w*8 + lrow)*H_ + (kt)*64 + k8; \
        __builtin_amdgcn_global_load_lds(AS_G(_s), AS_L(&Ab[sel][((r)*64 + w*8)*64]), 16, 0, 0); \
    } while(0)
#define STAGE_B(sel, r, kt) do { \
        const unsigned short* _s = wb + (size_t)(nbase + (r)*64 + w*8 + lrow)*H_ + (kt)*64 + k8; \
        __builtin_amdgcn_global_load_lds(AS_G(_s), AS_L(&Bb[sel][((r)*64 + w*8)*64]), 16, 0, 0); \
    } while(0)

#define LOADB(sel) \
    _Pragma("unroll") \
    for (int ni=0; ni<4; ++ni) { \
        const int brow = wc*64 + ni*16 + m; \
        bfr[ni][0] = *(const bf16x8*)(&Bb[sel][brow*64 + ((qh ^ rl))*8]); \
        bfr[ni][1] = *(const bf16x8*)(&Bb[sel][brow*64 + (((4+qh) ^ rl))*8]); \
    }
#define LOADA(sel, qq) \
    _Pragma("unroll") \
    for (int mi2=0; mi2<2; ++mi2) { \
        const int arow = wr*128 + ((qq)*2+mi2)*16 + m; \
        af[mi2][0] = *(const bf16x8*)(&Ab[sel][arow*64 + ((qh ^ rl))*8]); \
        af[mi2][1] = *(const bf16x8*)(&Ab[sel][arow*64 + (((4+qh) ^ rl))*8]); \
    }
#define MFMA16(qq) \
    __builtin_amdgcn_s_setprio(1); \
    _Pragma("unroll") \
    for (int mi2=0; mi2<2; ++mi2) \
        _Pragma("unroll") \
        for (int ni=0; ni<4; ++ni) { \
            acc[(qq)*2+mi2][ni] = __builtin_amdgcn_mfma_f32_16x16x32_bf16(af[mi2][0], bfr[ni][0], acc[(qq)*2+mi2][ni], 0, 0, 0); \
            acc[(qq)*2+mi2][ni] = __builtin_amdgcn_mfma_f32_16x16x32_bf16(af[mi2][1], bfr[ni][1], acc[(qq)*2+mi2][ni], 0, 0, 0); \
        } \
    __builtin_amdgcn_s_setprio(0);
#define BARX() __builtin_amdgcn_s_barrier()
#define WAIT_LGKM() do { asm volatile("s_waitcnt lgkmcnt(0)" ::: "memory"); \
                         __builtin_amdgcn_sched_barrier(0); } while(0)

    // ---- prologue: K-tile 0 -> buf0 (all), K-tile 1 -> buf1 (B + Ar1,Ar3)
    STAGE_B(0,0,0); STAGE_B(0,1,0);
    STAGE_B(0,2,0); STAGE_B(0,3,0);
    STAGE_A(0,1,0,mb_cur); STAGE_A(0,3,0,mb_cur);
    STAGE_A(0,0,0,mb_cur); STAGE_A(0,2,0,mb_cur);
    STAGE_B(1,0,1); STAGE_B(1,1,1);
    STAGE_B(1,2,1); STAGE_B(1,3,1);
    STAGE_A(1,1,1,mb_cur); STAGE_A(1,3,1,mb_cur);
    asm volatile("s_waitcnt vmcnt(6)" ::: "memory");   // buf0 fully landed
    BARX();

    #pragma unroll 1
    for (int mt = 0; mt < ntiles; ++mt) {
        const int mb_nxt = (ytile + 32*(mt+1)) * 256;  // used only when staged
        #pragma unroll 1
        for (int it = 0; it < 4; ++it) {
            const bool last = (mt == ntiles-1) && (it == 3);
            const int k1 = 2*it + 1;                   // buf1 A (current tile)
            const int k2 = (2*it + 2) & 7;             // rolls to next tile's kt0
            const int k3 = (2*it + 3) & 7;             // rolls to next tile's kt1
            const int mbs = (it < 3) ? mb_cur : mb_nxt;
            // ---- p1: buf0 q=3 + B hoist | stage buf1.Ar0,Ar2 (k1)
            LOADB(0) LOADA(0,3)
            STAGE_A(1,0,k1,mb_cur); STAGE_A(1,2,k1,mb_cur);
            BARX(); WAIT_LGKM();
            MFMA16(3)
            BARX();
            // ---- p2: q=2 | stage buf0.Br0,Br1 (k2)
            LOADA(0,2)
            if (!last) { STAGE_B(0,0,k2); STAGE_B(0,1,k2); }
            BARX(); WAIT_LGKM();
            MFMA16(2)
            BARX();
            // ---- p3: q=1 | stage buf0.Br2,Br3
            LOADA(0,1)
            if (!last) { STAGE_B(0,2,k2); STAGE_B(0,3,k2); }
            BARX(); WAIT_LGKM();
            MFMA16(1)
            BARX();
            // ---- p4: q=0 | stage buf0.Ar1,Ar3 | vmcnt
            LOADA(0,0)
            if (!last) { STAGE_A(0,1,k2,mbs); STAGE_A(0,3,k2,mbs); }
            BARX(); WAIT_LGKM();
            MFMA16(0)
            if (!last) { asm volatile("s_waitcnt vmcnt(6)" ::: "memory"); }
            else       { asm volatile("s_waitcnt vmcnt(0)" ::: "memory"); }
            BARX();
            // ---- p5: buf1 q=3 + B hoist | stage buf0.Ar0,Ar2 (k2)
            LOADB(1) LOADA(1,3)
            if (!last) { STAGE_A(0,0,k2,mbs); STAGE_A(0,2,k2,mbs); }
            BARX(); WAIT_LGKM();
            MFMA16(3)
            BARX();
            // ---- p6: q=2 | stage buf1.Br0,Br1 (k3)
            LOADA(1,2)
            if (!last) { STAGE_B(1,0,k3); STAGE_B(1,1,k3); }
            BARX(); WAIT_LGKM();
            MFMA16(2)
            BARX();
            // ---- p7: q=1 | stage buf1.Br2,Br3
            LOADA(1,1)
            if (!last) { STAGE_B(1,2,k3); STAGE_B(1,3,k3); }
            BARX(); WAIT_LGKM();
            MFMA16(1)
            BARX();
            // ---- p8: q=0 | stage buf1.Ar1,Ar3 | vmcnt
            LOADA(1,0)
            if (!last) { STAGE_A(1,1,k3,mbs); STAGE_A(1,3,k3,mbs); }
            BARX(); WAIT_LGKM();
            MFMA16(0)
            if (!last) { asm volatile("s_waitcnt vmcnt(6)" ::: "memory"); }
            else       { asm volatile("s_waitcnt vmcnt(0)" ::: "memory"); }
            BARX();
        }

        // ---- epilogue for mb_cur: bias + exp2 row-sum, DPP rowsum16 (VALU)
        // -> LDS atomic from m==15 lanes -> coalesced tid<256 global atomic.
        {
            #pragma unroll
            for (int mi=0;mi<8;mi++) {
                #pragma unroll
                for (int r=0;r<4;r++) {
                    float s = 0.f;
                    #pragma unroll
                    for (int ni=0;ni<4;ni++)
                        s += exp2f((acc[mi][ni][r] + bv[ni]) * LOG2E - LSE_SHIFT);
                    s = rowsum16(s);
                    if (m == 15) atomicAdd(&rs[wr*128 + mi*16 + qh*4 + r], s);
                }
            }
            WAIT_LGKM();
            BARX();
            if (tid < 256) {
                atomicAdd(&Srow[mb_cur + tid], rs[tid]);
                rs[tid] = 0.f;
            }
            #pragma unroll
            for (int i=0;i<8;i++)
                #pragma unroll
                for (int j=0;j<4;j++) acc[i][j] = (f32x4){0.f,0.f,0.f,0.f};
        }
        mb_cur = mb_nxt;
    }
#undef STAGE_A
#undef STAGE_B
#undef LOADB
#undef LOADA
#undef MFMA16
#undef BARX
#undef WAIT_LGKM
}

// ---------------------------------------------------------------------------
// Kernel 2: gather ext-label probs via MFMA (B-rows gathered by vocab id),
// same XOR bank swizzle as kernel 1.
// ---------------------------------------------------------------------------
__global__ __launch_bounds__(256) void gather_mfma_kernel(
        const unsigned short* __restrict__ eb, const unsigned short* __restrict__ wb,
        const float* __restrict__ bias, const int* __restrict__ ys,
        const float* __restrict__ Srow, float* __restrict__ g)
{
    __shared__ __align__(16) unsigned short As[128*64];
    __shared__ __align__(16) unsigned short Bs[128*64];
    __shared__ float ls[128];
    const int tid  = threadIdx.x;
    const int w    = tid >> 6;
    const int lane = tid & 63;
    const int m    = lane & 15;
    const int q    = lane >> 4;
    const int wrow = w >> 1;
    const int wcol = w & 1;
    const int b    = blockIdx.y;
    const int tb   = blockIdx.x * 128;

    if (tid < 128) {
        int t = tb + tid;
        ls[tid] = (t < T_) ? (LSE_SHIFT + log2f(Srow[b*T_ + t])) : 0.f;
    }

    const int rbase = w*32 + (lane >> 3);
    const int k8    = (((lane & 7) ^ ((lane >> 3) & 7)) * 8);
    const int rl    = m & 7;

    int vrow[4];
    #pragma unroll
    for (int j=0;j<4;++j) {
        int labr = rbase + j*8;
        vrow[j] = (labr == 0 || labr > L_) ? 0 : ys[b*L_ + labr - 1];
    }
    int labc[4]; float bv[4];
    #pragma unroll
    for (int ni=0;ni<4;++ni) {
        int lab = wcol*64 + ni*16 + m;
        labc[ni] = lab;
        int v = (lab == 0 || lab > L_) ? 0 : ys[b*L_ + lab - 1];
        bv[ni] = bias[v];
    }

    f32x4 acc[4][4];
    #pragma unroll
    for (int i=0;i<4;i++)
        #pragma unroll
        for (int j=0;j<4;j++) acc[i][j] = (f32x4){0.f,0.f,0.f,0.f};

    for (int kc = 0; kc < 8; ++kc) {
        __syncthreads();
        #pragma unroll
        for (int j = 0; j < 4; ++j) {
            const unsigned short* ga = eb + (size_t)(b*T_ + tb + rbase + j*8)*H_ + kc*64 + k8;
            __builtin_amdgcn_global_load_lds(AS_G(ga), AS_L(As + (w*4+j)*512), 16, 0, 0);
            const unsigned short* gw = wb + (size_t)vrow[j]*H_ + kc*64 + k8;
            __builtin_amdgcn_global_load_lds(AS_G(gw), AS_L(Bs + (w*4+j)*512), 16, 0, 0);
        }
        __syncthreads();
        #pragma unroll
        for (int kk = 0; kk < 2; ++kk) {
            const int sw = ((kk*4 + q) ^ rl) * 8;
            bf16x8 af[4], bfr[4];
            #pragma unroll
            for (int mi=0;mi<4;mi++)
                af[mi] = *(const bf16x8*)(As + (wrow*8 + mi*2 + (m>>3))*512 + rl*64 + sw);
            #pragma unroll
            for (int ni=0;ni<4;ni++)
                bfr[ni] = *(const bf16x8*)(Bs + (wcol*8 + ni*2 + (m>>3))*512 + rl*64 + sw);
            #pragma unroll
            for (int mi=0;mi<4;mi++)
                #pragma unroll
                for (int ni=0;ni<4;ni++)
                    acc[mi][ni] = __builtin_amdgcn_mfma_f32_16x16x32_bf16(
                        af[mi], bfr[ni], acc[mi][ni], 0, 0, 0);
        }
    }

    #pragma unroll
    for (int mi=0;mi<4;mi++) {
        #pragma unroll
        for (int r=0;r<4;r++) {
            int trow = wrow*64 + mi*16 + q*4 + r;
            int t = tb + trow;
            float l2 = ls[trow];
            #pragma unroll
            for (int ni=0;ni<4;ni++) {
                if (t < T_ && labc[ni] <= L_) {
                    float p = exp2f((acc[mi][ni][r] + bv[ni]) * LOG2E - l2);
                    int off = (labc[ni] == 0) ? 0 : labc[ni] + 1;
                    g[(size_t)(b*T_ + t)*GSTRIDE + off] = p;
                }
            }
        }
    }
}

// ---------------------------------------------------------------------------
// Kernel 3: CTC forward DP — producer/consumer waves, barrier-ordered
// (R5 version — best measured total 265.4 µs).
// ---------------------------------------------------------------------------
__global__ __launch_bounds__(128, 1) void ctc_dp_kernel(
        const float* __restrict__ g, const int* __restrict__ ys,
        const int* __restrict__ elens, const int* __restrict__ ylens,
        float* __restrict__ out)
{
    __shared__ __align__(16) float ring[2*2048];   // 2 sets x 8 pair-slots x 1KB
    const int b    = blockIdx.x;
    const int tid  = threadIdx.x;
    const int wv   = tid >> 6;
    const int lane = tid & 63;
    const float* gb = g + (size_t)b * T_ * GSTRIDE;
    const int ylen = ylens[b];
    const int elen = elens[b];
    const int kmax = (elen - 1) >> 4;

    const int Sv   = 2*ylen + 1;
    const int s0   = 4*lane;
    const float msk0 = (s0   < Sv) ? 1.f : 0.f;
    const float msk1 = (s0+1 < Sv) ? 1.f : 0.f;
    const float msk2 = (s0+2 < Sv) ? 1.f : 0.f;
    const float msk3 = (s0+3 < Sv) ? 1.f : 0.f;
    const int l0 = 2*lane, l1 = 2*lane + 1;
    int i0 = min(max(l0,1), L_-1);
    int i1 = min(l1, L_-1);
    const float sk1 = (l0 >= 1 && l0 < L_ && ys[b*L_+i0] != ys[b*L_+i0-1]) ? 1.f : 0.f;
    const float sk3 = (l1 < L_        && ys[b*L_+i1] != ys[b*L_+i1-1]) ? 1.f : 0.f;

    float a0 = 0.f, a1 = 0.f, a2 = 0.f, a3 = 0.f, C2 = 0.f;
    if (wv == 0) {
        a0 = (lane == 0) ? gb[0] : 0.f;     // t=0 init
        a1 = (lane == 0) ? gb[2] : 0.f;
    } else {
        #pragma unroll
        for (int s = 0; s < 8; ++s) {
            int srow = min(2*s, T_-2);
            __builtin_amdgcn_global_load_lds(AS_G(gb + (size_t)srow*GSTRIDE + 4*lane),
                                             AS_L(ring + s*256), 16, 0, 0);
        }
    }

    auto dpstep = [&](float p0, float p1, float p2, float p3) {
        float um1 = dpp_shr1(a3);
        float n0 = a0 + um1;
        float n1 = a1 + a0 + sk1*um1;
        float n2 = a2 + a1;
        float n3 = a3 + a2 + sk3*a1;
        a0 = n0*p0; a1 = n1*p1; a2 = n2*p2; a3 = n3*p3;
    };
    auto renorm = [&]() {
        float mm = wave_max_nonneg(fmaxf(fmaxf(a0,a1), fmaxf(a2,a3)));
        if (mm > 0.f) {
            float rr = fminf(__fdividef(BIAS60, mm), 3.0e38f);
            C2 -= __log2f(rr);
            a0 *= rr; a1 *= rr; a2 *= rr; a3 *= rr;
        }
    };

    __syncthreads();                                  // burst 0 landed

    for (int k = 0; k <= kmax; ++k) {
        if (wv == 1) {
            if (k < kmax) {
                float* dset = ring + ((k+1) & 1)*2048;
                int pbase = 8*(k + 1);
                #pragma unroll
                for (int s = 0; s < 8; ++s) {
                    int srow = min(2*(pbase + s), T_-2);
                    __builtin_amdgcn_global_load_lds(AS_G(gb + (size_t)srow*GSTRIDE + 4*lane),
                                                     AS_L(dset + s*256), 16, 0, 0);
                }
            }
        } else {
            const float* sb = ring + (k & 1)*2048;
            float P0[16], P1[16], P2[16], P3[16];
            #pragma unroll
            for (int s = 0; s < 8; ++s) {
                const float* slot = sb + s*256;
                float pb0 = slot[0];
                float pb1 = slot[104];
                float2 lo = *(const float2*)(slot + 2  + 2*lane);
                float2 hi = *(const float2*)(slot + 106 + 2*lane);
                P0[2*s]   = pb0*msk0; P1[2*s]   = lo.x*msk1;
                P2[2*s]   = pb0*msk2; P3[2*s]   = lo.y*msk3;
                P0[2*s+1] = pb1*msk0; P1[2*s+1] = hi.x*msk1;
                P2[2*s+1] = pb1*msk2; P3[2*s+1] = hi.y*msk3;
            }
            const int t0 = 16*k;
            #pragma unroll
            for (int j = 0; j < 16; ++j) {
                int t = t0 + j;
                if (t > 0 && t < elen)
                    dpstep(P0[j], P1[j], P2[j], P3[j]);
                if ((j & 7) == 7) renorm();
            }
        }
        __syncthreads();
    }

    if (wv == 0) {
        int sA = 2*ylen, sB = sA - 1;
        float vA = __shfl((sA & 2) ? a2 : a0, sA >> 2);
        float vB = __shfl((sB & 2) ? a3 : a1, sB >> 2);
        if (lane == 0) {
            float sum = vA + vB;
            float loss = 0.f;
            if (sum > 0.f) {
                loss = -(log2f(sum) + C2) * 0.6931471805599453f;
                if (!(loss < 5e9f)) loss = 0.f;         // zero_infinity
            }
            atomicAdd(out, loss * (1.0f/B_));
        }
    }
}

// ---------------------------------------------------------------------------
extern "C" void kernel_launch(void* const* d_in, const int* in_sizes, int n_in,
                              void* d_out, int out_size, void* d_ws, size_t ws_size,
                              hipStream_t stream)
{
    const float* eouts = (const float*)d_in[0];
    const float* W     = (const float*)d_in[1];
    const float* bias  = (const float*)d_in[2];
    const int*   ys    = (const int*)d_in[3];
    const int*   elens = (const int*)d_in[4];
    const int*   ylens = (const int*)d_in[5];
    float* out = (float*)d_out;

    char* ws = (char*)d_ws;
    unsigned short* eb = (unsigned short*)ws;                  // 32,768,000 B
    unsigned short* wb = (unsigned short*)(ws + 32768000);     //  2,097,152 B
    float* Srow        = (float*)(ws + 34865152);              //    128,000 B
    float* g           = (float*)(ws + 34993152);              // 13,312,000 B

    prep_kernel<<<17057, 256, 0, stream>>>(eouts, W, eb, wb, Srow, out);
    gemm_lse_kernel<<<256, 512, 0, stream>>>(eb, wb, bias, Srow);
    gather_mfma_kernel<<<dim3(8, 32), 256, 0, stream>>>(eb, wb, bias, ys, Srow, g);
    ctc_dp_kernel<<<B_, 128, 0, stream>>>(g, ys, elens, ylens, out);
}